// Round 4
// baseline (1108.309 us; speedup 1.0000x reference)
//
#include <hip/hip_runtime.h>
#include <hip/hip_bf16.h>
#include <stdint.h>

// Problem constants
#define M_ROWS 32768
#define N_CODES 8192
#define K_DIM 256
#define AK 512         // A storage: [zh | zl*2^6] per row (512 f16)
// B fragment store Bf[nb16][kt24][lane64][8]: logical k768 chunks:
//   chunk0 (k 0-255)   = eh*2^6, chunk1 (256-511) = el*2^6, chunk2 (512-767) = eh
// cross = acc * 2^-6; key = esq - 2*cross = fma(-2^-5, acc, esq)
// kt->A map: kt 0-7: zh, kt 8-15: zh (again), kt 16-23: zl   (matches R2 order
// exactly -> accs bit-identical to the R2 passing run)

#define BMP 64         // persistent block M-tile (A LDS = 64x512x2 = 64 KB)
#define NSTEP 256      // cols per nb-step; 32 steps cover N=8192

typedef _Float16 half8 __attribute__((ext_vector_type(8)));
typedef float f4v __attribute__((ext_vector_type(4)));
typedef float f32x4 __attribute__((ext_vector_type(4)));
typedef __attribute__((address_space(3))) void lds_void;
typedef const __attribute__((address_space(1))) void gbl_cvoid;

// Monotone map: fp32 bits -> uint32 preserving < order (handles sign)
__device__ __forceinline__ unsigned long long pack_key(float d, unsigned col) {
    unsigned u = __float_as_uint(d);
    u = (u & 0x80000000u) ? ~u : (u | 0x80000000u);
    return ((unsigned long long)u << 32) | (unsigned long long)col;
}

// ---------------- prep A: elementwise split (grid-stride, float4) -----------
__global__ __launch_bounds__(256) void prep_a(const float* __restrict__ z,
                                              _Float16* __restrict__ Aq) {
    typedef _Float16 h4v __attribute__((ext_vector_type(4)));
    int tid = blockIdx.x * 256 + threadIdx.x;
    const f4v* z4 = (const f4v*)z;
    #pragma unroll 1
    for (int i = tid; i < M_ROWS * (K_DIM / 4); i += 1024 * 256) {
        f4v v = z4[i];
        int row = i >> 6, c4 = i & 63;
        h4v hi, lo;
        #pragma unroll
        for (int j = 0; j < 4; ++j) {
            _Float16 h = (_Float16)v[j];
            hi[j] = h;
            lo[j] = (_Float16)((v[j] - (float)h) * 64.0f);
        }
        *(h4v*)&Aq[(size_t)row * AK + c4 * 4]         = hi;
        *(h4v*)&Aq[(size_t)row * AK + K_DIM + c4 * 4] = lo;
    }
}

// ---------------- prep esq: wave-per-row reduction --------------------------
__global__ __launch_bounds__(256) void prep_esq(const float* __restrict__ cb,
                                                float* __restrict__ esq) {
    int wave = threadIdx.x >> 6, lane = threadIdx.x & 63;
    int row = blockIdx.x * 4 + wave;                 // grid = 2048
    f4v v = *(const f4v*)(cb + (size_t)row * K_DIM + lane * 4);
    float sq = v[0]*v[0] + v[1]*v[1] + v[2]*v[2] + v[3]*v[3];
    #pragma unroll
    for (int m = 32; m; m >>= 1) sq += __shfl_xor(sq, m);
    if (lane == 0) esq[row] = sq;
}

// ---------------- prep Bf: codebook -> MFMA fragment layout -----------------
// Bf cell cid = ((nb16*24)+kt)*64+lane holds 8 halves:
//   code = nb16*16 + (lane&15), k768 = kt*32 + (lane>>4)*8 + j
__global__ __launch_bounds__(256) void prep_bf(const float* __restrict__ cb,
                                               half8* __restrict__ Bf) {
    int cid = blockIdx.x * 256 + threadIdx.x;        // grid 3072 -> 786432 cells
    int nb = cid / 1536;
    int r  = cid - nb * 1536;
    int kt = r >> 6, lane = r & 63;
    int code = nb * 16 + (lane & 15);
    int kq = kt * 32 + ((lane >> 4) << 3);
    int chunk = kq >> 8, k = kq & 255;
    const float* src = cb + (size_t)code * K_DIM + k;
    half8 o;
    #pragma unroll
    for (int j = 0; j < 8; ++j) {
        float x = src[j];
        _Float16 h = (_Float16)x;
        float hf = (float)h;
        o[j] = (chunk == 0) ? (_Float16)(hf * 64.0f)
             : (chunk == 1) ? (_Float16)((x - hf) * 64.0f)
             : h;
    }
    Bf[cid] = o;
}

// ---------------- main GEMM + fused argmin (barrier-free K-loop) ------------
__global__ __launch_bounds__(256, 2) void gemm_argmin(
        const _Float16* __restrict__ Aq, const half8* __restrict__ Bf,
        const float* __restrict__ esq,
        unsigned long long* __restrict__ best) {
    __shared__ __align__(16) _Float16 As[BMP * AK];  // 64 KB exactly

    int m0 = blockIdx.x * BMP;
    int t = threadIdx.x, lane = t & 63, wave = t >> 6;
    int quad = lane >> 4, l15 = lane & 15;
    int rswz = l15 & 7;

    // --- stage A once: 64 rows x 1024 B; unit u of row holds logical u^(row&7)
    const _Float16* Ag = Aq + (size_t)m0 * AK;
    #pragma unroll
    for (int it = 0; it < 16; ++it) {
        int row = it * 4 + wave;
        int srcu = lane ^ (row & 7);
        __builtin_amdgcn_global_load_lds(
            (gbl_cvoid*)(Ag + (size_t)row * AK + srcu * 8),
            (lds_void*)(As + row * AK),              // wave-uniform; +lane*16 HW
            16, 0, 0);
    }
    __syncthreads();                                 // the only barrier

    unsigned long long run[4][4];
    #pragma unroll
    for (int mi = 0; mi < 4; ++mi)
        #pragma unroll
        for (int r = 0; r < 4; ++r) run[mi][r] = ~0ULL;

    #pragma unroll 1
    for (int nbs = 0; nbs < 32; ++nbs) {
        int nbase16 = nbs * 16 + wave * 4;           // nb16 for ni=0
        const half8* Bb = Bf + (size_t)nbase16 * (24 * 64) + lane;
        int colbase = nbs * NSTEP + wave * 64 + l15;
        float es[4];
        #pragma unroll
        for (int ni = 0; ni < 4; ++ni) es[ni] = esq[colbase + ni * 16];

        f32x4 acc[4][4] = {};

        half8 b[4], bn[4];
        #pragma unroll
        for (int ni = 0; ni < 4; ++ni) b[ni] = Bb[ni * (24 * 64)];

        #pragma unroll
        for (int kt = 0; kt < 24; ++kt) {
            if (kt < 23) {                           // 1-deep B prefetch
                #pragma unroll
                for (int ni = 0; ni < 4; ++ni)
                    bn[ni] = Bb[ni * (24 * 64) + (kt + 1) * 64];
            }
            int v0 = (kt < 16) ? ((kt & 7) * 4 + quad)
                               : (32 + (kt & 7) * 4 + quad);
            half8 a[4];
            #pragma unroll
            for (int mi = 0; mi < 4; ++mi) {
                int rowA = mi * 16 + l15;
                a[mi] = *(const half8*)&As[rowA * AK + ((v0 ^ rswz) * 8)];
            }
            #pragma unroll
            for (int mi = 0; mi < 4; ++mi)
                #pragma unroll
                for (int ni = 0; ni < 4; ++ni)
                    acc[mi][ni] = __builtin_amdgcn_mfma_f32_16x16x32_f16(
                        a[mi], b[ni], acc[mi][ni], 0, 0, 0);
            #pragma unroll
            for (int ni = 0; ni < 4; ++ni) b[ni] = bn[ni];
        }

        // per-step epilogue: fold into per-lane running argmin (registers)
        #pragma unroll
        for (int mi = 0; mi < 4; ++mi)
            #pragma unroll
            for (int r = 0; r < 4; ++r) {
                unsigned long long bv = run[mi][r];
                #pragma unroll
                for (int ni = 0; ni < 4; ++ni) {
                    float key = fmaf(-0.03125f, acc[mi][ni][r], es[ni]);
                    unsigned long long p =
                        pack_key(key, (unsigned)(colbase + ni * 16));
                    bv = (p < bv) ? p : bv;
                }
                run[mi][r] = bv;
            }
    }

    // final cross-l15 reduce + one atomic per row per wave
    #pragma unroll
    for (int mi = 0; mi < 4; ++mi)
        #pragma unroll
        for (int r = 0; r < 4; ++r) {
            unsigned long long bv = run[mi][r];
            #pragma unroll
            for (int m = 1; m < 16; m <<= 1) {
                unsigned long long o =
                    (unsigned long long)__shfl_xor((long long)bv, m);
                bv = (o < bv) ? o : bv;
            }
            if (l15 == 0)
                atomicMin(&best[m0 + mi * 16 + quad * 4 + r], bv);
        }
}

// ---------------- ws-light fallback (only if ws too small) ------------------
__global__ __launch_bounds__(256) void vq_bruteforce(const float* __restrict__ z,
                                                     const float* __restrict__ cb,
                                                     float* __restrict__ out_idx) {
    __shared__ float As[128 * 16];
    __shared__ float Bs[128 * 16];
    int t = threadIdx.x;
    int tx = t & 15, ty = t >> 4;
    int r0 = blockIdx.x * 128;
    unsigned long long best[8];
    #pragma unroll
    for (int j = 0; j < 8; ++j) best[j] = ~0ULL;

    for (int n0 = 0; n0 < N_CODES; n0 += 128) {
        float acc[8][8] = {};
        for (int k0 = 0; k0 < K_DIM; k0 += 16) {
            __syncthreads();
            int row = t >> 1, c8 = (t & 1) * 8;
            #pragma unroll
            for (int j = 0; j < 8; ++j)
                As[row * 16 + c8 + j] = z[(size_t)(r0 + row) * K_DIM + k0 + c8 + j];
            #pragma unroll
            for (int j = 0; j < 8; ++j)
                Bs[row * 16 + c8 + j] = cb[(size_t)(n0 + row) * K_DIM + k0 + c8 + j];
            __syncthreads();
            #pragma unroll
            for (int k = 0; k < 16; ++k) {
                float a[8], b[8];
                #pragma unroll
                for (int j = 0; j < 8; ++j) a[j] = As[(ty * 8 + j) * 16 + k];
                #pragma unroll
                for (int j = 0; j < 8; ++j) b[j] = Bs[(tx * 8 + j) * 16 + k];
                #pragma unroll
                for (int i = 0; i < 8; ++i)
                    #pragma unroll
                    for (int j = 0; j < 8; ++j) {
                        float d = a[i] - b[j];
                        acc[i][j] += d * d;
                    }
            }
        }
        #pragma unroll
        for (int i = 0; i < 8; ++i) {
            unsigned long long bv = ~0ULL;
            #pragma unroll
            for (int j = 0; j < 8; ++j) {
                unsigned long long p =
                    pack_key(acc[i][j], (unsigned)(n0 + tx * 8 + j));
                bv = (p < bv) ? p : bv;
            }
            #pragma unroll
            for (int m = 1; m < 16; m <<= 1) {
                unsigned long long o =
                    (unsigned long long)__shfl_xor((long long)bv, m);
                bv = (o < bv) ? o : bv;
            }
            if (tx == 0 && bv < best[i]) best[i] = bv;
        }
    }
    if (tx == 0) {
        #pragma unroll
        for (int i = 0; i < 8; ++i)
            out_idx[r0 + ty * 8 + i] =
                (float)(unsigned)(best[i] & 0xFFFFFFFFULL);
    }
}

// ---------------- finalize: gather, straight-through out, loss sum ----------
__global__ __launch_bounds__(256) void finalize(const float* __restrict__ z,
                                                const float* __restrict__ cb,
                                                const unsigned long long* __restrict__ best,
                                                float* __restrict__ out,
                                                double* __restrict__ accum,
                                                int use_packed) {
    int wave = threadIdx.x >> 6, lane = threadIdx.x & 63;
    float* out_idx = out + (size_t)M_ROWS * K_DIM;
    float se = 0.f;
    #pragma unroll 1
    for (int row = blockIdx.x * 4 + wave; row < M_ROWS; row += 1024 * 4) {
        int idx = use_packed ? (int)(unsigned)(best[row] & 0xFFFFFFFFULL)
                             : (int)out_idx[row];
        f4v zv = *(const f4v*)(z  + (size_t)row * K_DIM + lane * 4);
        f4v qv = *(const f4v*)(cb + (size_t)idx * K_DIM + lane * 4);
        f4v ov;
        #pragma unroll
        for (int j = 0; j < 4; ++j) {
            float d = qv[j] - zv[j];                 // ref: z_q - z_e
            ov[j] = zv[j] + d;                       // ref: z_e + (z_q - z_e)
            se += d * d;
        }
        *(f4v*)(out + (size_t)row * K_DIM + lane * 4) = ov;
        if (lane == 0) out_idx[row] = (float)idx;
    }
    #pragma unroll
    for (int m = 32; m; m >>= 1) se += __shfl_xor(se, m);
    __shared__ float part[4];
    if (lane == 0) part[wave] = se;
    __syncthreads();
    if (threadIdx.x == 0)
        atomicAdd(accum, (double)((part[0] + part[1]) + (part[2] + part[3])));
}

__global__ void write_loss(const double* __restrict__ accum,
                           float* __restrict__ out) {
    // vq_loss = codebook_loss + 0.25*commitment_loss = 1.25 * mean(diff^2)
    out[(size_t)M_ROWS * K_DIM + M_ROWS] =
        (float)(1.25 * (*accum / (double)((size_t)M_ROWS * K_DIM)));
}

// ---------------- launch ----------------------------------------------------
extern "C" void kernel_launch(void* const* d_in, const int* in_sizes, int n_in,
                              void* d_out, int out_size, void* d_ws, size_t ws_size,
                              hipStream_t stream) {
    const float* z  = (const float*)d_in[0];
    const float* cb = (const float*)d_in[1];
    float* out = (float*)d_out;
    float* out_idx = out + (size_t)M_ROWS * K_DIM;

    size_t szA = (size_t)M_ROWS * AK * sizeof(_Float16);        // 32 MB
    size_t szB = (size_t)512 * 24 * 64 * 16;                    // 12 MB (Bf)
    size_t offB   = szA;
    size_t offE   = offB + szB;
    size_t offP   = offE + (size_t)N_CODES * sizeof(float);
    size_t offAcc = offP + (size_t)M_ROWS * sizeof(unsigned long long);
    size_t need   = offAcc + 16;

    if (ws_size >= need) {
        _Float16* Aq = (_Float16*)((char*)d_ws);
        half8* Bf    = (half8*)((char*)d_ws + offB);
        float* esq   = (float*)((char*)d_ws + offE);
        unsigned long long* packed = (unsigned long long*)((char*)d_ws + offP);
        double* accum = (double*)((char*)d_ws + offAcc);

        hipMemsetAsync((char*)d_ws + offP, 0xFF,
                       (size_t)M_ROWS * sizeof(unsigned long long), stream);
        hipMemsetAsync((char*)d_ws + offAcc, 0, sizeof(double), stream);

        prep_a<<<1024, 256, 0, stream>>>(z, Aq);
        prep_esq<<<N_CODES / 4, 256, 0, stream>>>(cb, esq);
        prep_bf<<<3072, 256, 0, stream>>>(cb, Bf);
        gemm_argmin<<<M_ROWS / BMP, 256, 0, stream>>>(Aq, Bf, esq, packed);
        finalize<<<1024, 256, 0, stream>>>(z, cb, packed, out, accum, 1);
        write_loss<<<1, 1, 0, stream>>>(accum, out);
    } else {
        double* accum = (double*)d_ws;
        hipMemsetAsync(d_ws, 0, sizeof(double), stream);
        vq_bruteforce<<<M_ROWS / 128, 256, 0, stream>>>(z, cb, out_idx);
        finalize<<<1024, 256, 0, stream>>>(z, cb, nullptr, out, accum, 0);
        write_loss<<<1, 1, 0, stream>>>(accum, out);
    }
}